// Round 1
// baseline (1461.120 us; speedup 1.0000x reference)
//
#include <hip/hip_runtime.h>
#include <math.h>

#define N_NODES 50000
#define N_EDGES 800000
#define DIM_IN 64
#define DIM_HID 128
#define DIM_OUT 64

#define EB 128      // edges per block
#define PAD 132     // LDS row stride (floats); mult of 4 for b128, 132%32=4 spreads banks

__device__ __forceinline__ float softplus_f(float v) {
    // numerically stable: max(v,0) + log1p(exp(-|v|))
    return fmaxf(v, 0.0f) + log1pf(expf(-fabsf(v)));
}

__global__ void zero_out_kernel(float4* __restrict__ out, int n4) {
    int i = blockIdx.x * blockDim.x + threadIdx.x;
    if (i < n4) out[i] = make_float4(0.f, 0.f, 0.f, 0.f);
}

// H: [EB][PAD] activations in LDS. Computes H = softplus(H @ W + b), K=J=128.
__device__ __forceinline__ void layer128(float* __restrict__ H,
                                         const float* __restrict__ W,
                                         const float* __restrict__ b,
                                         int te, int tj)
{
    float acc[8][8];
#pragma unroll
    for (int i = 0; i < 8; ++i)
#pragma unroll
        for (int u = 0; u < 8; ++u) acc[i][u] = 0.f;

    const float* Wp = W + tj * 8;
    for (int k = 0; k < 128; k += 4) {
        float4 a4[8];
#pragma unroll
        for (int i = 0; i < 8; ++i)
            a4[i] = *(const float4*)(H + (te + i * 16) * PAD + k);
        float w[4][8];
#pragma unroll
        for (int kk = 0; kk < 4; ++kk) {
            float4 wlo = *(const float4*)(Wp + (k + kk) * 128);
            float4 whi = *(const float4*)(Wp + (k + kk) * 128 + 4);
            w[kk][0] = wlo.x; w[kk][1] = wlo.y; w[kk][2] = wlo.z; w[kk][3] = wlo.w;
            w[kk][4] = whi.x; w[kk][5] = whi.y; w[kk][6] = whi.z; w[kk][7] = whi.w;
        }
#pragma unroll
        for (int i = 0; i < 8; ++i) {
            const float av[4] = {a4[i].x, a4[i].y, a4[i].z, a4[i].w};
#pragma unroll
            for (int kk = 0; kk < 4; ++kk)
#pragma unroll
                for (int u = 0; u < 8; ++u)
                    acc[i][u] = fmaf(av[kk], w[kk][u], acc[i][u]);
        }
    }

    float bv[8];
    {
        float4 blo = *(const float4*)(b + tj * 8);
        float4 bhi = *(const float4*)(b + tj * 8 + 4);
        bv[0] = blo.x; bv[1] = blo.y; bv[2] = blo.z; bv[3] = blo.w;
        bv[4] = bhi.x; bv[5] = bhi.y; bv[6] = bhi.z; bv[7] = bhi.w;
    }
    __syncthreads();   // all reads of H done before overwrite
#pragma unroll
    for (int i = 0; i < 8; ++i) {
        float o[8];
#pragma unroll
        for (int u = 0; u < 8; ++u) o[u] = softplus_f(acc[i][u] + bv[u]);
        *(float4*)(H + (te + i * 16) * PAD + tj * 8)     = make_float4(o[0], o[1], o[2], o[3]);
        *(float4*)(H + (te + i * 16) * PAD + tj * 8 + 4) = make_float4(o[4], o[5], o[6], o[7]);
    }
    __syncthreads();
}

__global__ __launch_bounds__(256, 2)
void edge_mlp_kernel(const float* __restrict__ x,
                     const int* __restrict__ eidx,
                     const float* __restrict__ W0, const float* __restrict__ b0,
                     const float* __restrict__ W1, const float* __restrict__ b1,
                     const float* __restrict__ W2, const float* __restrict__ b2,
                     float* __restrict__ out)
{
    __shared__ float H[EB * PAD];
    __shared__ int rowS[EB];
    __shared__ int colS[EB];

    const int tid = threadIdx.x;
    const int e0  = blockIdx.x * EB;
    const int* rowp = eidx;
    const int* colp = eidx + N_EDGES;

    if (tid < EB) {
        rowS[tid] = rowp[e0 + tid];
        colS[tid] = colp[e0 + tid];
    }
    __syncthreads();

    // ---- gather: H[e][0..64) = x[row[e]], H[e][64..128) = x[col[e]] ----
#pragma unroll
    for (int it = 0; it < 16; ++it) {
        int f = tid + it * 256;          // 0..4095 float4 slots
        int lane16 = f & 15;             // position within a 64-float half-row
        int seg = f >> 4;                // 0..255 = edge*2 + half
        int e = seg >> 1;
        int half = seg & 1;
        int src = half ? colS[e] : rowS[e];
        float4 v = *(const float4*)(x + (size_t)src * DIM_IN + lane16 * 4);
        *(float4*)(H + e * PAD + half * DIM_IN + lane16 * 4) = v;
    }
    __syncthreads();

    const int te = tid & 15;
    const int tj = tid >> 4;

    layer128(H, W0, b0, te, tj);   // h = softplus(h @ W0 + b0)
    layer128(H, W1, b1, te, tj);   // h = softplus(h @ W1 + b1)

    // ---- layer 2: K=128, J=64, no activation; scatter-add to out ----
    {
        float acc[8][4];
#pragma unroll
        for (int i = 0; i < 8; ++i)
#pragma unroll
            for (int u = 0; u < 4; ++u) acc[i][u] = 0.f;

        const float* Wp = W2 + tj * 4;
        for (int k = 0; k < 128; k += 4) {
            float4 a4[8];
#pragma unroll
            for (int i = 0; i < 8; ++i)
                a4[i] = *(const float4*)(H + (te + i * 16) * PAD + k);
            float4 w[4];
#pragma unroll
            for (int kk = 0; kk < 4; ++kk)
                w[kk] = *(const float4*)(Wp + (k + kk) * 64);
#pragma unroll
            for (int i = 0; i < 8; ++i) {
                const float av[4] = {a4[i].x, a4[i].y, a4[i].z, a4[i].w};
#pragma unroll
                for (int kk = 0; kk < 4; ++kk) {
                    acc[i][0] = fmaf(av[kk], w[kk].x, acc[i][0]);
                    acc[i][1] = fmaf(av[kk], w[kk].y, acc[i][1]);
                    acc[i][2] = fmaf(av[kk], w[kk].z, acc[i][2]);
                    acc[i][3] = fmaf(av[kk], w[kk].w, acc[i][3]);
                }
            }
        }

        float4 bb = *(const float4*)(b2 + tj * 4);
        const float bv[4] = {bb.x, bb.y, bb.z, bb.w};
#pragma unroll
        for (int i = 0; i < 8; ++i) {
            int e = te + i * 16;
            float* op = out + (size_t)rowS[e] * DIM_OUT + tj * 4;
#pragma unroll
            for (int u = 0; u < 4; ++u)
                atomicAdd(op + u, acc[i][u] + bv[u]);
        }
    }
}

extern "C" void kernel_launch(void* const* d_in, const int* in_sizes, int n_in,
                              void* d_out, int out_size, void* d_ws, size_t ws_size,
                              hipStream_t stream) {
    const float* x  = (const float*)d_in[0];
    const int*   ei = (const int*)d_in[1];
    const float* W0 = (const float*)d_in[2];
    const float* b0 = (const float*)d_in[3];
    const float* W1 = (const float*)d_in[4];
    const float* b1 = (const float*)d_in[5];
    const float* W2 = (const float*)d_in[6];
    const float* b2 = (const float*)d_in[7];
    float* out = (float*)d_out;

    const int n4 = (N_NODES * DIM_OUT) / 4;  // 800000 float4s
    zero_out_kernel<<<(n4 + 255) / 256, 256, 0, stream>>>((float4*)out, n4);
    edge_mlp_kernel<<<N_EDGES / EB, 256, 0, stream>>>(x, ei, W0, b0, W1, b1, W2, b2, out);
}

// Round 2
// 320.035 us; speedup vs baseline: 4.5655x; 4.5655x over previous
//
#include <hip/hip_runtime.h>
#include <math.h>

#define N_NODES 50000
#define N_EDGES 800000
#define DIM_IN 64
#define DIM_HID 128
#define DIM_OUT 64

#define EB  128   // edges per block
#define PAD 136   // bf16 elements per row in LDS / ws weight rows (136*2=272B, 16B-aligned)

typedef __attribute__((ext_vector_type(8))) short short8;   // 8 bf16 (4 VGPRs)
typedef __attribute__((ext_vector_type(4))) float f32x4;    // MFMA accumulator

// RTNE float->bf16 (branch-free; inputs are finite)
__device__ __forceinline__ unsigned short f2bf(float f) {
    unsigned u = __float_as_uint(f);
    unsigned r = (u + 0x7fffu + ((u >> 16) & 1u)) >> 16;
    return (unsigned short)r;
}

// fast softplus: max(x,0) + log(1+exp(-|x|)); abs err ~1e-7 with HW exp/log
__device__ __forceinline__ float softplus_f(float v) {
    float e = __expf(-fabsf(v));
    return fmaxf(v, 0.0f) + __logf(1.0f + e);
}

__global__ void zero_out_kernel(float4* __restrict__ out, int n4) {
    int i = blockIdx.x * blockDim.x + threadIdx.x;
    if (i < n4) out[i] = make_float4(0.f, 0.f, 0.f, 0.f);
}

// Convert W0,W1,W2 (fp32, [K][N] row-major) -> bf16 W^T [n][PAD] (k-contig) in ws
__global__ void prep_weights(const float* __restrict__ W0,
                             const float* __restrict__ W1,
                             const float* __restrict__ W2,
                             unsigned short* __restrict__ wt) {
    const int R = 128 * PAD;
    int i = blockIdx.x * blockDim.x + threadIdx.x;
    if (i < R) {
        int n = i / PAD, k = i - n * PAD;
        wt[i] = f2bf(k < 128 ? W0[k * DIM_HID + n] : 0.f);
    } else if (i < 2 * R) {
        int j = i - R;
        int n = j / PAD, k = j - n * PAD;
        wt[i] = f2bf(k < 128 ? W1[k * DIM_HID + n] : 0.f);
    } else if (i < 2 * R + 64 * PAD) {
        int j = i - 2 * R;
        int n = j / PAD, k = j - n * PAD;
        wt[i] = f2bf(k < 128 ? W2[k * DIM_OUT + n] : 0.f);
    }
}

__global__ __launch_bounds__(256, 2)
void edge_mlp_mfma(const float* __restrict__ x,
                   const int* __restrict__ eidx,
                   const unsigned short* __restrict__ wt,
                   const float* __restrict__ b0,
                   const float* __restrict__ b1,
                   const float* __restrict__ b2,
                   float* __restrict__ out) {
    __shared__ unsigned short Ha[EB * PAD];
    __shared__ int rowS[EB];
    __shared__ int colS[EB];

    const int tid = threadIdx.x;
    const int e0 = blockIdx.x * EB;

    if (tid < EB) {
        rowS[tid] = eidx[e0 + tid];
        colS[tid] = eidx[N_EDGES + e0 + tid];
    }
    __syncthreads();

    // ---- gather: Ha[e][0..128) = bf16(concat(x[row[e]], x[col[e]])) ----
#pragma unroll
    for (int it = 0; it < 16; ++it) {
        int f = tid + it * 256;            // 0..4095 float4 slots (128 rows x 32 chunks)
        int e = f >> 5;
        int c = f & 31;                    // float4 chunk within row
        int src = (c & 16) ? colS[e] : rowS[e];
        float4 v = *(const float4*)(x + (size_t)src * DIM_IN + (c & 15) * 4);
        unsigned p0 = f2bf(v.x) | ((unsigned)f2bf(v.y) << 16);
        unsigned p1 = f2bf(v.z) | ((unsigned)f2bf(v.w) << 16);
        *(uint2*)(Ha + e * PAD + c * 4) = make_uint2(p0, p1);
    }
    __syncthreads();

    const int lane = tid & 63;
    const int w = tid >> 6;
    const int wi = w & 1;          // m-half (rows wi*64..+64)
    const int wj = w >> 1;         // n-half (cols wj*64..+64)
    const int l16 = lane & 15;
    const int q = lane >> 4;

    const unsigned short* Wt0 = wt;
    const unsigned short* Wt1 = wt + 128 * PAD;
    const unsigned short* Wt2 = wt + 256 * PAD;

    // ---- layers 0,1: H = softplus(H @ W + b), 128->128 ----
#pragma unroll 1
    for (int layer = 0; layer < 2; ++layer) {
        const unsigned short* W = layer ? Wt1 : Wt0;
        const float* bias = layer ? b1 : b0;

        short8 afr[4][4];
#pragma unroll
        for (int ss = 0; ss < 4; ++ss)
#pragma unroll
            for (int kk = 0; kk < 4; ++kk)
                afr[ss][kk] = *(const short8*)(Ha + (wi * 64 + ss * 16 + l16) * PAD + kk * 32 + q * 8);
        __syncthreads();   // all A-preloads done before anyone overwrites Ha

        f32x4 acc[4][4];
#pragma unroll
        for (int ss = 0; ss < 4; ++ss)
#pragma unroll
            for (int tt = 0; tt < 4; ++tt)
                acc[ss][tt] = (f32x4){0.f, 0.f, 0.f, 0.f};

#pragma unroll
        for (int tt = 0; tt < 4; ++tt) {
            const unsigned short* Wp = W + (wj * 64 + tt * 16 + l16) * PAD + q * 8;
            short8 bfr[4];
#pragma unroll
            for (int kk = 0; kk < 4; ++kk)
                bfr[kk] = *(const short8*)(Wp + kk * 32);
#pragma unroll
            for (int ss = 0; ss < 4; ++ss)
#pragma unroll
                for (int kk = 0; kk < 4; ++kk)
                    acc[ss][tt] = __builtin_amdgcn_mfma_f32_16x16x32_bf16(
                        afr[ss][kk], bfr[kk], acc[ss][tt], 0, 0, 0);
        }

        // epilogue: bias + softplus -> bf16 back into Ha (C-layout: col=l16, row=q*4+r)
#pragma unroll
        for (int tt = 0; tt < 4; ++tt) {
            float bv = bias[wj * 64 + tt * 16 + l16];
#pragma unroll
            for (int ss = 0; ss < 4; ++ss) {
#pragma unroll
                for (int r = 0; r < 4; ++r) {
                    float vv = softplus_f(acc[ss][tt][r] + bv);
                    Ha[(wi * 64 + ss * 16 + q * 4 + r) * PAD + wj * 64 + tt * 16 + l16] = f2bf(vv);
                }
            }
        }
        __syncthreads();
    }

    // ---- layer 2: O = H @ W2 + b2 (128->64), scatter-add ----
    {
        short8 afr[4][4];
#pragma unroll
        for (int ss = 0; ss < 4; ++ss)
#pragma unroll
            for (int kk = 0; kk < 4; ++kk)
                afr[ss][kk] = *(const short8*)(Ha + (wi * 64 + ss * 16 + l16) * PAD + kk * 32 + q * 8);

        f32x4 acc[4][2];
#pragma unroll
        for (int ss = 0; ss < 4; ++ss)
#pragma unroll
            for (int tt = 0; tt < 2; ++tt)
                acc[ss][tt] = (f32x4){0.f, 0.f, 0.f, 0.f};

#pragma unroll
        for (int tt = 0; tt < 2; ++tt) {
            const unsigned short* Wp = Wt2 + (wj * 32 + tt * 16 + l16) * PAD + q * 8;
            short8 bfr[4];
#pragma unroll
            for (int kk = 0; kk < 4; ++kk)
                bfr[kk] = *(const short8*)(Wp + kk * 32);
#pragma unroll
            for (int ss = 0; ss < 4; ++ss)
#pragma unroll
                for (int kk = 0; kk < 4; ++kk)
                    acc[ss][tt] = __builtin_amdgcn_mfma_f32_16x16x32_bf16(
                        afr[ss][kk], bfr[kk], acc[ss][tt], 0, 0, 0);
        }

        float bv0 = b2[wj * 32 + l16];
        float bv1 = b2[wj * 32 + 16 + l16];
#pragma unroll
        for (int ss = 0; ss < 4; ++ss) {
#pragma unroll
            for (int r = 0; r < 4; ++r) {
                int row = wi * 64 + ss * 16 + q * 4 + r;
                int node = rowS[row];
                float* op = out + (size_t)node * DIM_OUT + wj * 32 + l16;
                atomicAdd(op, acc[ss][0][r] + bv0);
                atomicAdd(op + 16, acc[ss][1][r] + bv1);
            }
        }
    }
}

extern "C" void kernel_launch(void* const* d_in, const int* in_sizes, int n_in,
                              void* d_out, int out_size, void* d_ws, size_t ws_size,
                              hipStream_t stream) {
    const float* x  = (const float*)d_in[0];
    const int*   ei = (const int*)d_in[1];
    const float* W0 = (const float*)d_in[2];
    const float* b0 = (const float*)d_in[3];
    const float* W1 = (const float*)d_in[4];
    const float* b1 = (const float*)d_in[5];
    const float* W2 = (const float*)d_in[6];
    const float* b2 = (const float*)d_in[7];
    float* out = (float*)d_out;
    unsigned short* wt = (unsigned short*)d_ws;   // 87040 bytes used

    const int n4 = (N_NODES * DIM_OUT) / 4;
    zero_out_kernel<<<(n4 + 255) / 256, 256, 0, stream>>>((float4*)out, n4);

    const int wn = 2 * 128 * PAD + 64 * PAD;      // 43520 bf16 elements
    prep_weights<<<(wn + 255) / 256, 256, 0, stream>>>(W0, W1, W2, wt);

    edge_mlp_mfma<<<N_EDGES / EB, 256, 0, stream>>>(x, ei, wt, b0, b1, b2, out);
}

// Round 3
// 306.838 us; speedup vs baseline: 4.7619x; 1.0430x over previous
//
#include <hip/hip_runtime.h>
#include <math.h>

#define N_NODES 50000
#define N_EDGES 800000
#define DIM_IN 64
#define DIM_HID 128
#define DIM_OUT 64

#define EB  128   // edges per block (4 waves x 32 edges)
#define PAD 136   // bf16 per LDS/weight row: 272B, 16B-aligned, mult of 8

typedef __attribute__((ext_vector_type(8))) short short8;   // 8 bf16 (4 VGPRs)
typedef __attribute__((ext_vector_type(4))) float f32x4;    // MFMA accumulator

// RTNE float->bf16 (inputs finite)
__device__ __forceinline__ unsigned short f2bf(float f) {
    unsigned u = __float_as_uint(f);
    return (unsigned short)((u + 0x7fffu + ((u >> 16) & 1u)) >> 16);
}

__device__ __forceinline__ short8 pack8(float4 a, float4 b) {
    short8 f;
    f[0] = (short)f2bf(a.x); f[1] = (short)f2bf(a.y);
    f[2] = (short)f2bf(a.z); f[3] = (short)f2bf(a.w);
    f[4] = (short)f2bf(b.x); f[5] = (short)f2bf(b.y);
    f[6] = (short)f2bf(b.z); f[7] = (short)f2bf(b.w);
    return f;
}

// fast softplus: max(x,0) + log(1+exp(-|x|))
__device__ __forceinline__ float softplus_f(float v) {
    float e = __expf(-fabsf(v));
    return fmaxf(v, 0.0f) + __logf(1.0f + e);
}

// W0,W1,W2 (fp32 [K][N] row-major) -> bf16 W^T [n][PAD] (k-contiguous) in ws
__global__ void prep_weights(const float* __restrict__ W0,
                             const float* __restrict__ W1,
                             const float* __restrict__ W2,
                             unsigned short* __restrict__ wt) {
    const int R = 128 * PAD;
    int i = blockIdx.x * blockDim.x + threadIdx.x;
    if (i < R) {
        int n = i / PAD, k = i - n * PAD;
        wt[i] = f2bf(k < 128 ? W0[k * DIM_HID + n] : 0.f);
    } else if (i < 2 * R) {
        int j = i - R;
        int n = j / PAD, k = j - n * PAD;
        wt[i] = f2bf(k < 128 ? W1[k * DIM_HID + n] : 0.f);
    } else if (i < 2 * R + 64 * PAD) {
        int j = i - 2 * R;
        int n = j / PAD, k = j - n * PAD;
        wt[i] = f2bf(k < 128 ? W2[k * DIM_OUT + n] : 0.f);
    }
}

// MFMA block: acc[m][t] (+= bias-init done by caller), A in afr, B from wt rows
template <int NT>
__device__ __forceinline__ void mfma_layer(const short8 afr[2][4],
                                           const unsigned short* __restrict__ W,
                                           const float* __restrict__ bias,
                                           f32x4 acc[2][8], int l16, int q) {
#pragma unroll
    for (int t = 0; t < NT; ++t) {
        float bv = bias[t * 16 + l16];
#pragma unroll
        for (int m = 0; m < 2; ++m)
            acc[m][t] = (f32x4){bv, bv, bv, bv};
    }
#pragma unroll
    for (int t = 0; t < NT; ++t) {
        const unsigned short* Wp = W + (t * 16 + l16) * PAD + q * 8;
        short8 bfr[4];
#pragma unroll
        for (int kk = 0; kk < 4; ++kk)
            bfr[kk] = *(const short8*)(Wp + kk * 32);
#pragma unroll
        for (int m = 0; m < 2; ++m)
#pragma unroll
            for (int kk = 0; kk < 4; ++kk)
                acc[m][t] = __builtin_amdgcn_mfma_f32_16x16x32_bf16(
                    afr[m][kk], bfr[kk], acc[m][t], 0, 0, 0);
    }
}

__global__ __launch_bounds__(256, 3)
void edge_mlp_mfma(const float* __restrict__ x,
                   const int* __restrict__ eidx,
                   const unsigned short* __restrict__ wt,
                   const float* __restrict__ b0,
                   const float* __restrict__ b1,
                   const float* __restrict__ b2,
                   float* __restrict__ out) {
    __shared__ unsigned short Ha[4][32 * PAD];   // per-wave private slices

    const int tid  = threadIdx.x;
    const int lane = tid & 63;
    const int w    = tid >> 6;
    const int l16  = lane & 15;
    const int q    = lane >> 4;
    const int e0w  = blockIdx.x * EB + w * 32;   // this wave's 32 edges
    unsigned short* Hw = &Ha[w][0];

    const unsigned short* Wt0 = wt;
    const unsigned short* Wt1 = wt + 128 * PAD;
    const unsigned short* Wt2 = wt + 256 * PAD;

    // node indices for this lane's A-rows (edge = e0w + m*16 + l16)
    int rowI[2], colI[2];
#pragma unroll
    for (int m = 0; m < 2; ++m) {
        rowI[m] = eidx[e0w + m * 16 + l16];
        colI[m] = eidx[N_EDGES + e0w + m * 16 + l16];
    }

    // ---- layer 0: A-frags straight from x (concat(x[row],x[col]) in k) ----
    short8 afr[2][4];
#pragma unroll
    for (int m = 0; m < 2; ++m)
#pragma unroll
        for (int kk = 0; kk < 4; ++kk) {
            int node = (kk < 2) ? rowI[m] : colI[m];
            const float* p = x + (size_t)node * DIM_IN + (kk & 1) * 32 + q * 8;
            float4 va = *(const float4*)p;
            float4 vb = *(const float4*)(p + 4);
            afr[m][kk] = pack8(va, vb);
        }

    f32x4 acc[2][8];
    mfma_layer<8>(afr, Wt0, b0, acc, l16, q);

    // epilogue 0: softplus -> bf16 -> Hw (C-layout: row=q*4+r, col=l16)
#pragma unroll
    for (int m = 0; m < 2; ++m)
#pragma unroll
        for (int t = 0; t < 8; ++t)
#pragma unroll
            for (int r = 0; r < 4; ++r)
                Hw[(m * 16 + q * 4 + r) * PAD + t * 16 + l16] =
                    f2bf(softplus_f(acc[m][t][r]));
    asm volatile("s_waitcnt lgkmcnt(0)" ::: "memory");   // wave-local RAW fence

    // ---- layer 1 ----
#pragma unroll
    for (int m = 0; m < 2; ++m)
#pragma unroll
        for (int kk = 0; kk < 4; ++kk)
            afr[m][kk] = *(const short8*)(Hw + (m * 16 + l16) * PAD + kk * 32 + q * 8);

    mfma_layer<8>(afr, Wt1, b1, acc, l16, q);

#pragma unroll
    for (int m = 0; m < 2; ++m)
#pragma unroll
        for (int t = 0; t < 8; ++t)
#pragma unroll
            for (int r = 0; r < 4; ++r)
                Hw[(m * 16 + q * 4 + r) * PAD + t * 16 + l16] =
                    f2bf(softplus_f(acc[m][t][r]));
    asm volatile("s_waitcnt lgkmcnt(0)" ::: "memory");

    // ---- layer 2 (N=64) + scatter ----
#pragma unroll
    for (int m = 0; m < 2; ++m)
#pragma unroll
        for (int kk = 0; kk < 4; ++kk)
            afr[m][kk] = *(const short8*)(Hw + (m * 16 + l16) * PAD + kk * 32 + q * 8);

    mfma_layer<4>(afr, Wt2, b2, acc, l16, q);

#pragma unroll
    for (int m = 0; m < 2; ++m)
#pragma unroll
        for (int r = 0; r < 4; ++r) {
            int node = eidx[e0w + m * 16 + q * 4 + r];   // L1-hot reload
            float* op = out + (size_t)node * DIM_OUT + l16;
            atomicAdd(op,      acc[m][0][r]);
            atomicAdd(op + 16, acc[m][1][r]);
            atomicAdd(op + 32, acc[m][2][r]);
            atomicAdd(op + 48, acc[m][3][r]);
        }
}

extern "C" void kernel_launch(void* const* d_in, const int* in_sizes, int n_in,
                              void* d_out, int out_size, void* d_ws, size_t ws_size,
                              hipStream_t stream) {
    const float* x  = (const float*)d_in[0];
    const int*   ei = (const int*)d_in[1];
    const float* W0 = (const float*)d_in[2];
    const float* b0 = (const float*)d_in[3];
    const float* W1 = (const float*)d_in[4];
    const float* b1 = (const float*)d_in[5];
    const float* W2 = (const float*)d_in[6];
    const float* b2 = (const float*)d_in[7];
    float* out = (float*)d_out;
    unsigned short* wt = (unsigned short*)d_ws;   // 87040 bytes used

    hipMemsetAsync(out, 0, (size_t)N_NODES * DIM_OUT * sizeof(float), stream);

    const int wn = 2 * 128 * PAD + 64 * PAD;      // 43520 bf16 elements
    prep_weights<<<(wn + 255) / 256, 256, 0, stream>>>(W0, W1, W2, wt);

    edge_mlp_mfma<<<N_EDGES / EB, 256, 0, stream>>>(x, ei, wt, b0, b1, b2, out);
}